// Round 4
// baseline (120.727 us; speedup 1.0000x reference)
//
#include <hip/hip_runtime.h>
#include <stdint.h>

#define B_ROWS 1024
#define FEAT   256
#define QSZ    32768
#define SHIFT  1024
#define QX     (QSZ - B_ROWS)   // 31744
#define BM     64               // q-rows per GEMM block
#define NGY    (QSZ / BM)       // 512 blocks == partial slices per x-col
#define MARGIN 8.0f             // covers bf16 noise (~2) + key quantization (~2.5/side)

typedef float  v4f __attribute__((ext_vector_type(4)));
typedef short  v8s __attribute__((ext_vector_type(8)));

// ---------- packed score keys: orderable(m)[31:15] | j[14:0] ----------
__device__ __forceinline__ uint32_t key_flip(uint32_t u) {
    return u ^ ((uint32_t)((int32_t)u >> 31) | 0x80000000u);
}
__device__ __forceinline__ float key_m(uint32_t k) {  // floor-approx m back from key
    uint32_t u = k & 0xFFFF8000u;
    u = (u & 0x80000000u) ? (u ^ 0x80000000u) : ~u;
    return __uint_as_float(u);
}
__device__ __forceinline__ void k2_insert(uint32_t& k1, uint32_t& k2, uint32_t key) {
    uint32_t hi = max(k1, key); k1 = min(k1, key); k2 = min(k2, hi);
}
__device__ __forceinline__ uint2 k2_merge(uint2 a, uint2 b) {
    uint32_t hi = max(a.x, b.x);
    uint2 r; r.x = min(a.x, b.x); r.y = min(min(a.y, b.y), hi);
    return r;
}

// ---------- exact-score top2 (float + index tie-break, matches top_k) ----------
struct Top2 { float m1; int j1; float m2; int j2; };
__device__ __forceinline__ bool better(float ma, int ja, float mb, int jb) {
    return (ma < mb) || (ma == mb && ja < jb);
}
__device__ __forceinline__ void t2_insert(Top2& t, float m, int j) {
    if (better(m, j, t.m1, t.j1)) { t.m2 = t.m1; t.j2 = t.j1; t.m1 = m; t.j1 = j; }
    else if (better(m, j, t.m2, t.j2)) { t.m2 = m; t.j2 = j; }
}

__device__ __forceinline__ const float* q_row_ptr(int j, const float* x, const float* queue) {
    return (j < QX) ? (queue + (size_t)(j + SHIFT) * FEAT) : (x + (size_t)(j - QX) * FEAT);
}

__device__ __forceinline__ unsigned short f2bf(float f) {  // round-to-nearest-even
    uint32_t u = __float_as_uint(f);
    uint32_t r = u + 0x7FFFu + ((u >> 16) & 1u);
    return (unsigned short)(r >> 16);
}

// ---------- kernel 1 (tiny): x -> bf16 (B side of the GEMM; 512 KB, L2/L3-resident) ----------
__global__ __launch_bounds__(256) void convert_x(const float* __restrict__ x,
                                                 unsigned short* __restrict__ x_bf) {
    int wave = threadIdx.x >> 6, lane = threadIdx.x & 63;
    int r = blockIdx.x * 4 + wave;  // 0..1023
    float4 v = ((const float4*)(x + (size_t)r * FEAT))[lane];
    ushort4 h;
    h.x = f2bf(v.x); h.y = f2bf(v.y); h.z = f2bf(v.z); h.w = f2bf(v.w);
    ((ushort4*)x_bf)[(size_t)r * 64 + lane] = h;
}

// ---------- kernel 2: barrier-free register GEMM with in-kernel A conversion ----------
// One block = 64 q-rows x ALL 1024 x-cols. A converted f32->bf16 ONCE into
// swizzled LDS (phys granule pg of row r holds logical g=(pg&24)|((pg&7)^(r&7)));
// q2 computed on the fly. After ONE __syncthreads, all 32 A-fragments are pulled
// into registers (128 VGPR) -> zero LDS/barrier traffic in the main loop.
// B fragments load DIRECTLY from global (x_bf L2-resident) into double-buffered
// registers. Per-16-col epilogue is register-only (quad shuffle merge).
__global__ __launch_bounds__(256, 2) void nn_gemm(const float* __restrict__ x,
                                                  const float* __restrict__ queue,
                                                  const unsigned short* __restrict__ x_bf,
                                                  float* __restrict__ q2,
                                                  uint2* __restrict__ partials) {
    __shared__ __align__(16) unsigned short As[BM * FEAT];  // 32 KB swizzled A tile
    __shared__ __align__(16) float sq2[BM];

    const int t    = threadIdx.x;
    const int w    = t >> 6, lane = t & 63;
    const int quad = lane >> 4, l16 = lane & 15;
    const int gy   = blockIdx.x;

    // ---- B frags for tn=0: issue first so they're in flight during A conversion ----
    const unsigned short* bbase = x_bf + (size_t)(w * 256 + l16) * FEAT + quad * 8;
    v8s fb0[8], fb1[8];
#pragma unroll
    for (int kc = 0; kc < 8; ++kc) fb0[kc] = *(const v8s*)(bbase + kc * 32);

    // ---- A stage: 64 rows f32 -> bf16 swizzled LDS, q2 on the fly (round-2-verified) ----
    {
        const int arow = t >> 2, aqtr = t & 3;         // 4 threads per row, 64 feats each
        const float* asrc = q_row_ptr(gy * BM + arow, x, queue) + aqtr * 64;
        float ss = 0.0f;
#pragma unroll
        for (int gi = 0; gi < 8; ++gi) {               // 8 granules of 8 feats
            float4 a = *(const float4*)(asrc + gi * 8);
            float4 b = *(const float4*)(asrc + gi * 8 + 4);
            ss += a.x * a.x + a.y * a.y + a.z * a.z + a.w * a.w
                + b.x * b.x + b.y * b.y + b.z * b.z + b.w * b.w;
            uint32_t p0 = (uint32_t)f2bf(a.x) | ((uint32_t)f2bf(a.y) << 16);
            uint32_t p1 = (uint32_t)f2bf(a.z) | ((uint32_t)f2bf(a.w) << 16);
            uint32_t p2 = (uint32_t)f2bf(b.x) | ((uint32_t)f2bf(b.y) << 16);
            uint32_t p3 = (uint32_t)f2bf(b.z) | ((uint32_t)f2bf(b.w) << 16);
            const int g    = aqtr * 8 + gi;
            const int phys = (g & 24) | ((g & 7) ^ (arow & 7));
            *(uint4*)&As[arow * FEAT + phys * 8] = make_uint4(p0, p1, p2, p3);
        }
        ss += __shfl_xor(ss, 1, 64);                   // combine the 4 quarter-sums
        ss += __shfl_xor(ss, 2, 64);
        if (aqtr == 0) { sq2[arow] = ss; q2[gy * BM + arow] = ss; }
    }

    __syncthreads();  // the only block barrier: A tile + sq2 resident

    // ---- all 32 A-fragments into registers (row = tm*16+l16, k = kc*32+quad*8) ----
    v8s fa[4][8];
#pragma unroll
    for (int tm = 0; tm < 4; ++tm)
#pragma unroll
        for (int kc = 0; kc < 8; ++kc) {
            const int g  = kc * 4 + quad;
            const int pg = (g & 24) | ((g & 7) ^ (l16 & 7));
            fa[tm][kc] = *(const v8s*)((const char*)As + (size_t)(tm * 16 + l16) * 512 + pg * 16);
        }

    float q2r[4][4];
#pragma unroll
    for (int tm = 0; tm < 4; ++tm) {
        v4f qq = *(const v4f*)&sq2[tm * 16 + quad * 4];
#pragma unroll
        for (int r = 0; r < 4; ++r) q2r[tm][r] = qq[r];
    }

    // ---- per-16-col pipeline: 32 MFMA + register-only top2 epilogue ----
    auto process = [&](int tn, const v8s (&fb)[8]) {
        v4f acc[4] = {(v4f)0.0f, (v4f)0.0f, (v4f)0.0f, (v4f)0.0f};
#pragma unroll
        for (int kc = 0; kc < 8; ++kc)
#pragma unroll
            for (int tm = 0; tm < 4; ++tm)
                acc[tm] = __builtin_amdgcn_mfma_f32_16x16x32_bf16(fa[tm][kc], fb[kc], acc[tm], 0, 0, 0);
        uint32_t k1 = 0xFFFFFFFFu, k2 = 0xFFFFFFFFu;
        const int jb = gy * BM + quad * 4;
#pragma unroll
        for (int tm = 0; tm < 4; ++tm)
#pragma unroll
            for (int r = 0; r < 4; ++r) {
                float m = fmaf(-2.0f, acc[tm][r], q2r[tm][r]);
                uint32_t u = key_flip(__float_as_uint(m));
                uint32_t key = (u & 0xFFFF8000u) | (uint32_t)(jb + tm * 16 + r);
                k2_insert(k1, k2, key);
            }
        // merge across quads (x-col lives in lanes l16, +16, +32, +48)
#pragma unroll
        for (int mask = 16; mask <= 32; mask <<= 1) {
            uint32_t o1 = __shfl_xor(k1, mask, 64);
            uint32_t o2 = __shfl_xor(k2, mask, 64);
            uint32_t hi = max(k1, o1);
            k1 = min(k1, o1);
            k2 = min(min(k2, o2), hi);
        }
        if (quad == 0)
            partials[(size_t)(w * 256 + tn * 16 + l16) * NGY + gy] = make_uint2(k1, k2);
    };

    for (int tp = 0; tp < 8; ++tp) {   // NOT unrolled: keep loop body I-cache-sized
        const int tn0 = tp * 2;
        // prefetch odd-half B while computing even-half
#pragma unroll
        for (int kc = 0; kc < 8; ++kc)
            fb1[kc] = *(const v8s*)(bbase + (size_t)(tn0 + 1) * (16 * FEAT) + kc * 32);
        process(tn0, fb0);
        if (tp < 7) {
#pragma unroll
            for (int kc = 0; kc < 8; ++kc)
                fb0[kc] = *(const v8s*)(bbase + (size_t)(tn0 + 2) * (16 * FEAT) + kc * 32);
        }
        process(tn0 + 1, fb1);
    }
}

// ---------- kernel 3: key-based cutoff + exact f32 rescore + gather ----------
__global__ __launch_bounds__(256) void nn_finalize(const float* __restrict__ x,
                                                   const float* __restrict__ queue,
                                                   const float* __restrict__ q2,
                                                   const uint2* __restrict__ partials,
                                                   float* __restrict__ out) {
    __shared__ float    xs[256];
    __shared__ uint2    red[256];
    __shared__ int      list[64];
    __shared__ float    escore[64];
    __shared__ int      s_cnt;
    __shared__ uint32_t s_kcut;
    __shared__ int      s_j2;

    const int t = threadIdx.x, i = blockIdx.x;
    const int w = t >> 6, lane = t & 63;

    xs[t] = x[(size_t)i * FEAT + t];
    uint2 pa = partials[(size_t)i * NGY + t];
    uint2 pb = partials[(size_t)i * NGY + 256 + t];
    uint2 pm = k2_merge(pa, pb);   // merging preserves global-top2 candidacy
    red[t] = pm;
    if (t == 0) s_cnt = 0;
    __syncthreads();

    if (w == 0) {  // approx global top2 (keys) -> cutoff key
        uint2 a = red[lane];
        a = k2_merge(a, red[lane + 64]);
        a = k2_merge(a, red[lane + 128]);
        a = k2_merge(a, red[lane + 192]);
#pragma unroll
        for (int mask = 1; mask <= 32; mask <<= 1) {
            uint2 o;
            o.x = __shfl_xor(a.x, mask, 64);
            o.y = __shfl_xor(a.y, mask, 64);
            a = k2_merge(a, o);
        }
        if (lane == 0) {
            float cutf = key_m(a.y) + MARGIN;
            s_kcut = key_flip(__float_as_uint(cutf)) | 0x7FFFu;
        }
    }
    __syncthreads();
    uint32_t kcut = s_kcut;
    if (pm.x <= kcut) { int q_ = atomicAdd(&s_cnt, 1); if (q_ < 64) list[q_] = (int)(pm.x & 0x7FFFu); }
    if (pm.y <= kcut) { int q_ = atomicAdd(&s_cnt, 1); if (q_ < 64) list[q_] = (int)(pm.y & 0x7FFFu); }
    __syncthreads();
    int n = min(s_cnt, 64);

    for (int c = w; c < n; c += 4) {  // exact f32 rescore, one candidate per wave
        int j = list[c];
        const float4* qr = (const float4*)q_row_ptr(j, x, queue);
        float4 qv = qr[lane];
        float4 xv = ((const float4*)xs)[lane];
        float s = qv.x * xv.x + qv.y * xv.y + qv.z * xv.z + qv.w * xv.w;
#pragma unroll
        for (int off = 32; off; off >>= 1) s += __shfl_xor(s, off, 64);
        if (lane == 0) escore[c] = q2[j] - 2.0f * s;
    }
    __syncthreads();
    if (t == 0) {
        Top2 a;
        a.m1 = __builtin_inff(); a.j1 = 0x7FFFFFFF;
        a.m2 = __builtin_inff(); a.j2 = 0x7FFFFFFF;
        for (int c = 0; c < n; ++c) t2_insert(a, escore[c], list[c]);
        s_j2 = a.j2;  // second-nearest (nearest is self)
    }
    __syncthreads();
    out[(size_t)i * FEAT + t] = q_row_ptr(s_j2, x, queue)[t];
}

extern "C" void kernel_launch(void* const* d_in, const int* in_sizes, int n_in,
                              void* d_out, int out_size, void* d_ws, size_t ws_size,
                              hipStream_t stream) {
    const float* x     = (const float*)d_in[0];
    const float* queue = (const float*)d_in[1];

    unsigned short* x_bf     = (unsigned short*)d_ws;                    // 512 KB
    float*          q2       = (float*)((char*)d_ws + (1u << 20));       // 128 KB
    uint2*          partials = (uint2*)((char*)d_ws + (2u << 20));       // 4 MB

    convert_x<<<B_ROWS / 4, 256, 0, stream>>>(x, x_bf);
    nn_gemm<<<NGY, 256, 0, stream>>>(x, queue, x_bf, q2, partials);
    nn_finalize<<<B_ROWS, 256, 0, stream>>>(x, queue, q2, partials, (float*)d_out);
}

// Round 5
// 120.222 us; speedup vs baseline: 1.0042x; 1.0042x over previous
//
#include <hip/hip_runtime.h>
#include <stdint.h>

#define B_ROWS 1024
#define FEAT   256
#define QSZ    32768
#define SHIFT  1024
#define QX     (QSZ - B_ROWS)   // 31744
#define BM     64               // q-rows per GEMM block
#define NGY    (QSZ / BM)       // 512 blocks == partial slices per x-col
#define NCOL   1024             // x columns
#define MARGIN 8.0f             // covers bf16 noise (~2) + key quantization (~2.5/side)

typedef float  v4f __attribute__((ext_vector_type(4)));
typedef short  v8s __attribute__((ext_vector_type(8)));

// ---------- packed score keys: orderable(m)[31:15] | j[14:0] ----------
__device__ __forceinline__ uint32_t key_flip(uint32_t u) {
    return u ^ ((uint32_t)((int32_t)u >> 31) | 0x80000000u);
}
__device__ __forceinline__ float key_m(uint32_t k) {  // floor-approx m back from key
    uint32_t u = k & 0xFFFF8000u;
    u = (u & 0x80000000u) ? (u ^ 0x80000000u) : ~u;
    return __uint_as_float(u);
}
__device__ __forceinline__ void k2_insert(uint32_t& k1, uint32_t& k2, uint32_t key) {
    uint32_t hi = max(k1, key); k1 = min(k1, key); k2 = min(k2, hi);
}
__device__ __forceinline__ uint2 k2_merge(uint2 a, uint2 b) {
    uint32_t hi = max(a.x, b.x);
    uint2 r; r.x = min(a.x, b.x); r.y = min(min(a.y, b.y), hi);
    return r;
}

// ---------- exact-score top2 (float + index tie-break, matches top_k) ----------
struct Top2 { float m1; int j1; float m2; int j2; };
__device__ __forceinline__ bool better(float ma, int ja, float mb, int jb) {
    return (ma < mb) || (ma == mb && ja < jb);
}
__device__ __forceinline__ void t2_insert(Top2& t, float m, int j) {
    if (better(m, j, t.m1, t.j1)) { t.m2 = t.m1; t.j2 = t.j1; t.m1 = m; t.j1 = j; }
    else if (better(m, j, t.m2, t.j2)) { t.m2 = m; t.j2 = j; }
}

__device__ __forceinline__ const float* q_row_ptr(int j, const float* x, const float* queue) {
    return (j < QX) ? (queue + (size_t)(j + SHIFT) * FEAT) : (x + (size_t)(j - QX) * FEAT);
}

__device__ __forceinline__ unsigned short f2bf(float f) {  // round-to-nearest-even
    uint32_t u = __float_as_uint(f);
    uint32_t r = u + 0x7FFFu + ((u >> 16) & 1u);
    return (unsigned short)(r >> 16);
}

// ---------- kernel 1 (tiny): x -> bf16 (B side of the GEMM; 512 KB, L2/L3-resident) ----------
__global__ __launch_bounds__(256) void convert_x(const float* __restrict__ x,
                                                 unsigned short* __restrict__ x_bf) {
    int wave = threadIdx.x >> 6, lane = threadIdx.x & 63;
    int r = blockIdx.x * 4 + wave;  // 0..1023
    float4 v = ((const float4*)(x + (size_t)r * FEAT))[lane];
    ushort4 h;
    h.x = f2bf(v.x); h.y = f2bf(v.y); h.z = f2bf(v.z); h.w = f2bf(v.w);
    ((ushort4*)x_bf)[(size_t)r * 64 + lane] = h;
}

// ---------- kernel 2: barrier-free register GEMM, spill-proof codegen ----------
// One block = 64 q-rows x ALL 1024 x-cols. A converted f32->bf16 once into
// swizzled LDS, q2 on the fly; after ONE __syncthreads all 32 A-fragments live
// in registers (fa0..fa3, static indices only — NO lambda, NO by-ref arrays,
// tp loop fully unrolled so every fb access is compile-time static).
// B fragments load directly from L2-resident x_bf into double-buffered regs.
// partials layout [gy][col] -> the quad==0 store is 16 lanes x 128 B contiguous.

#define KEYI(ACC, Q2V, J)                                                  \
    {                                                                      \
        float m_ = fmaf(-2.0f, (ACC), (Q2V));                              \
        uint32_t u_ = key_flip(__float_as_uint(m_));                       \
        k2_insert(k1, k2, (u_ & 0xFFFF8000u) | (uint32_t)(J));             \
    }

#define PROCESS(TN, FB)                                                    \
    {                                                                      \
        v4f a0 = (v4f)0.0f, a1 = (v4f)0.0f, a2 = (v4f)0.0f, a3 = (v4f)0.0f;\
        __builtin_amdgcn_s_setprio(1);                                     \
        _Pragma("unroll")                                                  \
        for (int kc = 0; kc < 8; ++kc) {                                   \
            a0 = __builtin_amdgcn_mfma_f32_16x16x32_bf16(fa0[kc], FB[kc], a0, 0, 0, 0); \
            a1 = __builtin_amdgcn_mfma_f32_16x16x32_bf16(fa1[kc], FB[kc], a1, 0, 0, 0); \
            a2 = __builtin_amdgcn_mfma_f32_16x16x32_bf16(fa2[kc], FB[kc], a2, 0, 0, 0); \
            a3 = __builtin_amdgcn_mfma_f32_16x16x32_bf16(fa3[kc], FB[kc], a3, 0, 0, 0); \
        }                                                                  \
        __builtin_amdgcn_s_setprio(0);                                     \
        uint32_t k1 = 0xFFFFFFFFu, k2 = 0xFFFFFFFFu;                       \
        _Pragma("unroll")                                                  \
        for (int r = 0; r < 4; ++r) {                                      \
            KEYI(a0[r], q2r0[r], jb + 0  + r);                             \
            KEYI(a1[r], q2r1[r], jb + 16 + r);                             \
            KEYI(a2[r], q2r2[r], jb + 32 + r);                             \
            KEYI(a3[r], q2r3[r], jb + 48 + r);                             \
        }                                                                  \
        _Pragma("unroll")                                                  \
        for (int mask = 16; mask <= 32; mask <<= 1) {                      \
            uint32_t o1 = __shfl_xor(k1, mask, 64);                        \
            uint32_t o2 = __shfl_xor(k2, mask, 64);                        \
            uint32_t hi = max(k1, o1);                                     \
            k1 = min(k1, o1);                                              \
            k2 = min(min(k2, o2), hi);                                     \
        }                                                                  \
        if (quad == 0)                                                     \
            partials[(size_t)gy * NCOL + (w * 256 + (TN) * 16 + l16)] =    \
                make_uint2(k1, k2);                                        \
    }

__global__ __launch_bounds__(256, 2) void nn_gemm(const float* __restrict__ x,
                                                  const float* __restrict__ queue,
                                                  const unsigned short* __restrict__ x_bf,
                                                  float* __restrict__ q2,
                                                  uint2* __restrict__ partials) {
    __shared__ __align__(16) unsigned short As[BM * FEAT];  // 32 KB swizzled A tile
    __shared__ __align__(16) float sq2[BM];

    const int t    = threadIdx.x;
    const int w    = t >> 6, lane = t & 63;
    const int quad = lane >> 4, l16 = lane & 15;
    const int gy   = blockIdx.x;

    // ---- B frags for tn=0: issue first so they're in flight during A conversion ----
    const unsigned short* bbase = x_bf + (size_t)(w * 256 + l16) * FEAT + quad * 8;
    v8s fb0[8], fb1[8];
#pragma unroll
    for (int kc = 0; kc < 8; ++kc) fb0[kc] = *(const v8s*)(bbase + kc * 32);

    // ---- A stage: 64 rows f32 -> bf16 swizzled LDS, q2 on the fly (verified r2/r4) ----
    {
        const int arow = t >> 2, aqtr = t & 3;         // 4 threads per row, 64 feats each
        const float* asrc = q_row_ptr(gy * BM + arow, x, queue) + aqtr * 64;
        float ss = 0.0f;
#pragma unroll
        for (int gi = 0; gi < 8; ++gi) {               // 8 granules of 8 feats
            float4 a = *(const float4*)(asrc + gi * 8);
            float4 b = *(const float4*)(asrc + gi * 8 + 4);
            ss += a.x * a.x + a.y * a.y + a.z * a.z + a.w * a.w
                + b.x * b.x + b.y * b.y + b.z * b.z + b.w * b.w;
            uint32_t p0 = (uint32_t)f2bf(a.x) | ((uint32_t)f2bf(a.y) << 16);
            uint32_t p1 = (uint32_t)f2bf(a.z) | ((uint32_t)f2bf(a.w) << 16);
            uint32_t p2 = (uint32_t)f2bf(b.x) | ((uint32_t)f2bf(b.y) << 16);
            uint32_t p3 = (uint32_t)f2bf(b.z) | ((uint32_t)f2bf(b.w) << 16);
            const int g    = aqtr * 8 + gi;
            const int phys = (g & 24) | ((g & 7) ^ (arow & 7));
            *(uint4*)&As[arow * FEAT + phys * 8] = make_uint4(p0, p1, p2, p3);
        }
        ss += __shfl_xor(ss, 1, 64);                   // combine the 4 quarter-sums
        ss += __shfl_xor(ss, 2, 64);
        if (aqtr == 0) { sq2[arow] = ss; q2[gy * BM + arow] = ss; }
    }

    __syncthreads();  // the only block barrier: A tile + sq2 resident

    // ---- all 32 A-fragments into registers (row = tm*16+l16, k = kc*32+quad*8) ----
    v8s fa0[8], fa1[8], fa2[8], fa3[8];
#pragma unroll
    for (int kc = 0; kc < 8; ++kc) {
        const int g  = kc * 4 + quad;
        const int pg = (g & 24) | ((g & 7) ^ (l16 & 7));
        const char* rowb = (const char*)As + (size_t)l16 * 512 + pg * 16;
        fa0[kc] = *(const v8s*)(rowb);
        fa1[kc] = *(const v8s*)(rowb + 1 * 16 * 512);
        fa2[kc] = *(const v8s*)(rowb + 2 * 16 * 512);
        fa3[kc] = *(const v8s*)(rowb + 3 * 16 * 512);
    }

    v4f q2r0 = *(const v4f*)&sq2[ 0 + quad * 4];
    v4f q2r1 = *(const v4f*)&sq2[16 + quad * 4];
    v4f q2r2 = *(const v4f*)&sq2[32 + quad * 4];
    v4f q2r3 = *(const v4f*)&sq2[48 + quad * 4];
    const int jb = gy * BM + quad * 4;

    // ---- main loop: fully unrolled, double-buffered B, zero barriers ----
#pragma unroll
    for (int tp = 0; tp < 8; ++tp) {
        const int tn0 = tp * 2;
#pragma unroll
        for (int kc = 0; kc < 8; ++kc)
            fb1[kc] = *(const v8s*)(bbase + (size_t)(tn0 + 1) * (16 * FEAT) + kc * 32);
        PROCESS(tn0, fb0);
        if (tp < 7) {
#pragma unroll
            for (int kc = 0; kc < 8; ++kc)
                fb0[kc] = *(const v8s*)(bbase + (size_t)(tn0 + 2) * (16 * FEAT) + kc * 32);
        }
        PROCESS(tn0 + 1, fb1);
    }
}

// ---------- kernel 3: key-based cutoff + exact f32 rescore + gather ----------
__global__ __launch_bounds__(256) void nn_finalize(const float* __restrict__ x,
                                                   const float* __restrict__ queue,
                                                   const float* __restrict__ q2,
                                                   const uint2* __restrict__ partials,
                                                   float* __restrict__ out) {
    __shared__ float    xs[256];
    __shared__ uint2    red[256];
    __shared__ int      list[64];
    __shared__ float    escore[64];
    __shared__ int      s_cnt;
    __shared__ uint32_t s_kcut;
    __shared__ int      s_j2;

    const int t = threadIdx.x, i = blockIdx.x;
    const int w = t >> 6, lane = t & 63;

    xs[t] = x[(size_t)i * FEAT + t];
    uint2 pa = partials[(size_t)t * NCOL + i];          // gy = t
    uint2 pb = partials[(size_t)(t + 256) * NCOL + i];  // gy = t + 256
    uint2 pm = k2_merge(pa, pb);   // merging preserves global-top2 candidacy
    red[t] = pm;
    if (t == 0) s_cnt = 0;
    __syncthreads();

    if (w == 0) {  // approx global top2 (keys) -> cutoff key
        uint2 a = red[lane];
        a = k2_merge(a, red[lane + 64]);
        a = k2_merge(a, red[lane + 128]);
        a = k2_merge(a, red[lane + 192]);
#pragma unroll
        for (int mask = 1; mask <= 32; mask <<= 1) {
            uint2 o;
            o.x = __shfl_xor(a.x, mask, 64);
            o.y = __shfl_xor(a.y, mask, 64);
            a = k2_merge(a, o);
        }
        if (lane == 0) {
            float cutf = key_m(a.y) + MARGIN;
            s_kcut = key_flip(__float_as_uint(cutf)) | 0x7FFFu;
        }
    }
    __syncthreads();
    uint32_t kcut = s_kcut;
    if (pm.x <= kcut) { int q_ = atomicAdd(&s_cnt, 1); if (q_ < 64) list[q_] = (int)(pm.x & 0x7FFFu); }
    if (pm.y <= kcut) { int q_ = atomicAdd(&s_cnt, 1); if (q_ < 64) list[q_] = (int)(pm.y & 0x7FFFu); }
    __syncthreads();
    int n = min(s_cnt, 64);

    for (int c = w; c < n; c += 4) {  // exact f32 rescore, one candidate per wave
        int j = list[c];
        const float4* qr = (const float4*)q_row_ptr(j, x, queue);
        float4 qv = qr[lane];
        float4 xv = ((const float4*)xs)[lane];
        float s = qv.x * xv.x + qv.y * xv.y + qv.z * xv.z + qv.w * xv.w;
#pragma unroll
        for (int off = 32; off; off >>= 1) s += __shfl_xor(s, off, 64);
        if (lane == 0) escore[c] = q2[j] - 2.0f * s;
    }
    __syncthreads();
    if (t == 0) {
        Top2 a;
        a.m1 = __builtin_inff(); a.j1 = 0x7FFFFFFF;
        a.m2 = __builtin_inff(); a.j2 = 0x7FFFFFFF;
        for (int c = 0; c < n; ++c) t2_insert(a, escore[c], list[c]);
        s_j2 = a.j2;  // second-nearest (nearest is self)
    }
    __syncthreads();
    out[(size_t)i * FEAT + t] = q_row_ptr(s_j2, x, queue)[t];
}

extern "C" void kernel_launch(void* const* d_in, const int* in_sizes, int n_in,
                              void* d_out, int out_size, void* d_ws, size_t ws_size,
                              hipStream_t stream) {
    const float* x     = (const float*)d_in[0];
    const float* queue = (const float*)d_in[1];

    unsigned short* x_bf     = (unsigned short*)d_ws;                    // 512 KB
    float*          q2       = (float*)((char*)d_ws + (1u << 20));       // 128 KB
    uint2*          partials = (uint2*)((char*)d_ws + (2u << 20));       // 4 MB

    convert_x<<<B_ROWS / 4, 256, 0, stream>>>(x, x_bf);
    nn_gemm<<<NGY, 256, 0, stream>>>(x, queue, x_bf, q2, partials);
    nn_finalize<<<B_ROWS, 256, 0, stream>>>(x, queue, q2, partials, (float*)d_out);
}